// Round 7
// baseline (10914.256 us; speedup 1.0000x reference)
//
#include <hip/hip_runtime.h>
#include <stdint.h>
#include <stddef.h>

// GRU (B=32, T=2048, I=H=512, fp32 in/out).
// Phase 1: gz/gr = x@Wxz|Wxr + bias (fp16 MFMA GEMM) written INTO d_out
//   (row (b,t) of gzr == row (b,t) of out; scan consumes before overwriting).
// Phase 2: persistent scan, 256 WGs x 1024 threads = 32 batches x 8 slices.
//   Resident weights only 64 u32/thread (fits the 128-VGPR allocation the
//   backend insists on; R4-R6 proved it won't allocate more):
//     z/r: 16-way K-split of the 512 h-rows (32 words)
//     cand: 2-way K-split of slice's 64 rh-rows + 64 x-rows (32 words)
//   Cross-WG exchange: tagged-u64 self-synchronizing P/z buffers (as R3).

#define AGENT __HIP_MEMORY_SCOPE_AGENT

typedef _Float16 h2v __attribute__((ext_vector_type(2)));
typedef _Float16 half8 __attribute__((ext_vector_type(8)));
typedef float f32x4 __attribute__((ext_vector_type(4)));

__device__ __forceinline__ uint32_t pk2u(float a, float b) {
  h2v r; r[0] = (_Float16)a; r[1] = (_Float16)b;
  return __builtin_bit_cast(uint32_t, r);
}
__device__ __forceinline__ h2v bc2(uint32_t u) { return __builtin_bit_cast(h2v, u); }
__device__ __forceinline__ float dot2f(h2v a, h2v b, float c) {
#if __has_builtin(__builtin_amdgcn_fdot2)
  return __builtin_amdgcn_fdot2(a, b, c, false);
#else
  return fmaf((float)a[1], (float)b[1], fmaf((float)a[0], (float)b[0], c));
#endif
}
__device__ __forceinline__ float sigmoidf_(float x) { return 1.0f / (1.0f + __expf(-x)); }
__device__ __forceinline__ float tanhf_(float x) { return 1.0f - 2.0f / (1.0f + __expf(2.0f * x)); }
__device__ __forceinline__ uint64_t ald64(const uint64_t* p) {
  return __hip_atomic_load(p, __ATOMIC_RELAXED, AGENT);
}
__device__ __forceinline__ void ast64(uint64_t* p, uint64_t v) {
  __hip_atomic_store(p, v, __ATOMIC_RELAXED, AGENT);
}

// ---------------- Phase 1: gzr GEMM  [65536 x 512] @ [512 x 1024] -> fp16 ----------------
__global__ __launch_bounds__(256) void gemm_gzr(const float* __restrict__ x,
                                                const float* __restrict__ Wx,
                                                const float* __restrict__ bias,
                                                _Float16* __restrict__ gzr) {
  __shared__ alignas(16) _Float16 Alds[128 * 68];  // [m][k], stride 68 (136 B)
  __shared__ alignas(16) _Float16 Blds[128 * 68];  // [n][k]
  const int tid = threadIdx.x;
  const int bid = blockIdx.x;
  const int tm = bid >> 3, tn = bid & 7;
  const int m0 = tm << 7, n0 = tn << 7;  // n0 in [0,1024)
  const int lane = tid & 63;
  const int wv = tid >> 6, wm = wv >> 1, wn = wv & 1;
  const int l15 = lane & 15, lhi = lane >> 4;
  f32x4 acc[4][4] = {};

  for (int k0 = 0; k0 < 512; k0 += 64) {
    // A stage: x fp32 -> fp16, [128 m][64 k]
#pragma unroll
    for (int r = 0; r < 8; ++r) {
      int m = r * 16 + (tid >> 4);
      int k = (tid & 15) * 4;
      float4 v = *(const float4*)&x[(size_t)(m0 + m) * 512 + k0 + k];
      union { _Float16 h[4]; uint2 u; } cv;
      cv.h[0] = (_Float16)v.x; cv.h[1] = (_Float16)v.y;
      cv.h[2] = (_Float16)v.z; cv.h[3] = (_Float16)v.w;
      *(uint2*)&Alds[m * 68 + k] = cv.u;
    }
    // B stage: W columns (transpose on the fly), [128 n][64 k]
#pragma unroll
    for (int u = 0; u < 8; ++u) {
      int n = tid & 127;
      int k = (tid >> 7) * 32 + u * 4;
      int ng = n0 + n;
      const float* wp = Wx + ((size_t)(ng >> 9) << 18) + (size_t)(k0 + k) * 512 + (ng & 511);
      union { _Float16 h[4]; uint2 u2; } cv;
      cv.h[0] = (_Float16)wp[0];    cv.h[1] = (_Float16)wp[512];
      cv.h[2] = (_Float16)wp[1024]; cv.h[3] = (_Float16)wp[1536];
      *(uint2*)&Blds[n * 68 + k] = cv.u2;
    }
    __syncthreads();
#pragma unroll
    for (int kk = 0; kk < 2; ++kk) {
      int q = kk * 4 + lhi;  // 8-fp16 chunk index within BK=64
      half8 af[4], bf[4];
#pragma unroll
      for (int fm = 0; fm < 4; ++fm) {
        const _Float16* pa = &Alds[(wm * 64 + fm * 16 + l15) * 68 + q * 8];
        union { uint2 u[2]; half8 h; } cv;
        cv.u[0] = *(const uint2*)pa; cv.u[1] = *(const uint2*)(pa + 4);
        af[fm] = cv.h;
      }
#pragma unroll
      for (int fn = 0; fn < 4; ++fn) {
        const _Float16* pb = &Blds[(wn * 64 + fn * 16 + l15) * 68 + q * 8];
        union { uint2 u[2]; half8 h; } cv;
        cv.u[0] = *(const uint2*)pb; cv.u[1] = *(const uint2*)(pb + 4);
        bf[fn] = cv.h;
      }
#pragma unroll
      for (int fm = 0; fm < 4; ++fm)
#pragma unroll
        for (int fn = 0; fn < 4; ++fn)
          acc[fm][fn] = __builtin_amdgcn_mfma_f32_16x16x32_f16(af[fm], bf[fn], acc[fm][fn], 0, 0, 0);
    }
    __syncthreads();
  }
  // epilogue: D map col=lane&15, row=(lane>>4)*4+q2 (m89-verified); + bias; fp16 store
#pragma unroll
  for (int fn = 0; fn < 4; ++fn) {
    int col = n0 + wn * 64 + fn * 16 + l15;
    float bv = bias[((col >> 9) << 9) + (col & 511)];
#pragma unroll
    for (int fm = 0; fm < 4; ++fm) {
#pragma unroll
      for (int q2 = 0; q2 < 4; ++q2) {
        int row = m0 + wm * 64 + fm * 16 + lhi * 4 + q2;
        gzr[(size_t)row * 1024 + col] = (_Float16)(acc[fm][fn][q2] + bv);
      }
    }
  }
}

// ---------------- Phase 2: persistent scan ----------------
__global__ __launch_bounds__(1024) void gru_scan(
    const float* __restrict__ x,    // [32][2048][512]
    const float* __restrict__ Wx,   // [3][512][512] (Wxh used)
    const float* __restrict__ Wh,   // [3][512][512]
    const float* __restrict__ bias, // [3][512]
    const _Float16* gzr,            // [65536][1024] (aliases out!)
    float* out,                     // [32][2048][512] + [32][512]
    uint64_t* __restrict__ Pbuf,    // [2][32][8][512] tagged
    uint64_t* __restrict__ zbuf) {  // [2][32][512] tagged
  __shared__ _Float16 h16[512];
  __shared__ _Float16 x16s[64];   // x_t at this WG's slice rows
  __shared__ _Float16 rh16[64];   // r*h at this WG's slice rows
  __shared__ float Pparts[2][512];

  const int T = threadIdx.x;
  const int bid = blockIdx.x;
  const int xcd = bid & 7, ii = bid >> 3;
  const int batch = xcd * 4 + (ii >> 3);  // 8 WGs/batch share an XCD (heuristic)
  const int slice = ii & 7;
  const int c = T >> 4, s = T & 15;       // z/r: column-in-slice, 16-way K-split
  const int jg = slice * 64 + c;
  const int n = T & 511, half = T >> 9;   // P: output column, 2-way K-split

  // ---- resident weights: 64 u32/thread ----
  uint32_t wz2[16], wr2[16], wh2[16], wx2[16];
  {
    const float* Whz = Wh;
    const float* Whr = Wh + 262144;
#pragma unroll
    for (int j = 0; j < 8; ++j) {
      int p = (j + s) & 7;        // rotation: conflict-light h16 b64 reads
      int k = s * 32 + 4 * p;
#pragma unroll
      for (int q = 0; q < 2; ++q) {
        int kk = k + 2 * q;
        wz2[2 * j + q] = pk2u(Whz[(size_t)kk * 512 + jg], Whz[(size_t)(kk + 1) * 512 + jg]);
        wr2[2 * j + q] = pk2u(Whr[(size_t)kk * 512 + jg], Whr[(size_t)(kk + 1) * 512 + jg]);
      }
    }
    const float* Whh = Wh + 524288;
    const float* Wxh = Wx + 524288;
#pragma unroll
    for (int j = 0; j < 8; ++j) {
      int k = slice * 64 + half * 32 + 4 * j;
#pragma unroll
      for (int q = 0; q < 2; ++q) {
        int kk = k + 2 * q;
        wh2[2 * j + q] = pk2u(Whh[(size_t)kk * 512 + n], Whh[(size_t)(kk + 1) * 512 + n]);
        wx2[2 * j + q] = pk2u(Wxh[(size_t)kk * 512 + n], Wxh[(size_t)(kk + 1) * 512 + n]);
      }
    }
  }
#pragma unroll
  for (int i = 0; i < 16; ++i) {
    asm volatile("" : "+v"(wz2[i]));
    asm volatile("" : "+v"(wr2[i]));
    asm volatile("" : "+v"(wh2[i]));
    asm volatile("" : "+v"(wx2[i]));
  }
  const float bh = bias[1024 + n];

  float hreg = 0.0f;
  if (half == 0) h16[n] = (_Float16)0.0f;

  // prefetch step 0 inputs
  const size_t rowbase = (size_t)batch * 2048;
  _Float16 gz_p = gzr[rowbase * 1024 + jg];
  _Float16 gr_p = gzr[rowbase * 1024 + 512 + jg];
  float x_p = (T < 64) ? x[rowbase * 512 + slice * 64 + T] : 0.f;

  uint64_t* Pmine = Pbuf + ((size_t)batch * 8 + slice) * 512 + n;  // + po
  const uint64_t* Pread = Pbuf + ((size_t)batch * 8) * 512 + n;
  uint64_t* zmine = zbuf + (size_t)batch * 512 + jg;               // + zo
  const uint64_t* zread = zbuf + (size_t)batch * 512 + n;

  for (int t = 0; t < 2048; ++t) {
    if (t > 0) {
      // combine step t-1: spin-gather 8 tagged partials + tagged z for col n
      const size_t po = ((t - 1) & 1) ? 131072 : 0;
      const size_t zo = ((t - 1) & 1) ? 16384 : 0;
      const uint32_t want = (uint32_t)t;
      uint64_t v[8];
#pragma unroll
      for (int g = 0; g < 8; ++g) v[g] = ald64(Pread + po + (size_t)g * 512);
      uint64_t zv = ald64(zread + zo);
      for (;;) {
        bool ok = true;
        if ((uint32_t)(zv >> 32) != want) { zv = ald64(zread + zo); ok = false; }
#pragma unroll
        for (int g = 0; g < 8; ++g)
          if ((uint32_t)(v[g] >> 32) != want) { v[g] = ald64(Pread + po + (size_t)g * 512); ok = false; }
        if (ok) break;
        __builtin_amdgcn_s_sleep(1);
      }
      float hsum = 0.f;
#pragma unroll
      for (int g = 0; g < 8; ++g) hsum += __uint_as_float((uint32_t)v[g]);
      float zf = __uint_as_float((uint32_t)zv);
      float htil = tanhf_(bh + hsum);
      float hn = fmaf(zf, htil - hreg, hreg);
      if (slice == 0 && half == 0) out[(rowbase + (t - 1)) * 512 + n] = hn;
      hreg = hn;
      if (half == 0) h16[n] = (_Float16)hn;
    }
    float gzc = (float)gz_p, grc = (float)gr_p;
    if (T < 64) x16s[T] = (_Float16)x_p;
    __syncthreads();  // B1: h16/x16 published
    if (t < 2047) {   // prefetch step t+1 (consumed next iter; rows never clobbered early)
      size_t r1 = rowbase + t + 1;
      gz_p = gzr[r1 * 1024 + jg];
      gr_p = gzr[r1 * 1024 + 512 + jg];
      if (T < 64) x_p = x[r1 * 512 + slice * 64 + T];
    }

    // ---- z/r GEMV (h-part only; K=512, 16-way split) ----
    float za = 0.f, ra = 0.f;
#pragma unroll
    for (int j = 0; j < 8; ++j) {
      int p = (j + s) & 7;
      int k = s * 32 + 4 * p;
      uint2 hu = *(const uint2*)&h16[k];  // ds_read_b64
      za = dot2f(bc2(hu.x), bc2(wz2[2 * j]), za);
      za = dot2f(bc2(hu.y), bc2(wz2[2 * j + 1]), za);
      ra = dot2f(bc2(hu.x), bc2(wr2[2 * j]), ra);
      ra = dot2f(bc2(hu.y), bc2(wr2[2 * j + 1]), ra);
    }
#pragma unroll
    for (int d = 1; d < 16; d <<= 1) { za += __shfl_xor(za, d); ra += __shfl_xor(ra, d); }
    const size_t po = (t & 1) ? 131072 : 0;
    const size_t zo = (t & 1) ? 16384 : 0;
    const uint64_t tagw = ((uint64_t)(uint32_t)(t + 1)) << 32;
    float z = sigmoidf_(za + gzc);  // gz has bias folded
    float r = sigmoidf_(ra + grc);
    if (s == 0) {
      rh16[c] = (_Float16)(r * (float)h16[jg]);
      ast64(zmine + zo, tagw | (uint32_t)__float_as_uint(z));
    }
    __syncthreads();  // B2: rh16 visible

    // ---- candidate partial: rh_slice@Whh + x_slice@Wxh (2-way K-split) ----
    float pa = 0.f;
#pragma unroll
    for (int j = 0; j < 8; ++j) {
      uint2 ru = *(const uint2*)&rh16[half * 32 + 4 * j];  // uniform -> broadcast
      uint2 xu = *(const uint2*)&x16s[half * 32 + 4 * j];
      pa = dot2f(bc2(ru.x), bc2(wh2[2 * j]), pa);
      pa = dot2f(bc2(ru.y), bc2(wh2[2 * j + 1]), pa);
      pa = dot2f(bc2(xu.x), bc2(wx2[2 * j]), pa);
      pa = dot2f(bc2(xu.y), bc2(wx2[2 * j + 1]), pa);
    }
    Pparts[half][n] = pa;
    __syncthreads();  // B3: Pparts complete (also fences this step's LDS reads)
    if (half == 0) {
      float ps = Pparts[0][n] + Pparts[1][n];
      ast64(Pmine + po, tagw | (uint32_t)__float_as_uint(ps));
    }
  }

  // epilogue: finalize step 2047 (parity 1, tag 2048)
  {
    const uint32_t want = 2048u;
    uint64_t v[8];
#pragma unroll
    for (int g = 0; g < 8; ++g) v[g] = ald64(Pread + 131072 + (size_t)g * 512);
    uint64_t zv = ald64(zread + 16384);
    for (;;) {
      bool ok = true;
      if ((uint32_t)(zv >> 32) != want) { zv = ald64(zread + 16384); ok = false; }
#pragma unroll
      for (int g = 0; g < 8; ++g)
        if ((uint32_t)(v[g] >> 32) != want) { v[g] = ald64(Pread + 131072 + (size_t)g * 512); ok = false; }
      if (ok) break;
      __builtin_amdgcn_s_sleep(1);
    }
    float hsum = 0.f;
#pragma unroll
    for (int g = 0; g < 8; ++g) hsum += __uint_as_float((uint32_t)v[g]);
    float zf = __uint_as_float((uint32_t)zv);
    float htil = tanhf_(bh + hsum);
    float hn = fmaf(zf, htil - hreg, hreg);
    if (slice == 0 && half == 0) {
      out[(rowbase + 2047) * 512 + n] = hn;
      out[(size_t)32 * 2048 * 512 + (size_t)batch * 512 + n] = hn;
    }
  }
}

extern "C" void kernel_launch(void* const* d_in, const int* in_sizes, int n_in,
                              void* d_out, int out_size, void* d_ws, size_t ws_size,
                              hipStream_t stream) {
  (void)in_sizes; (void)n_in; (void)out_size; (void)ws_size;
  const float* x    = (const float*)d_in[0];
  const float* Wx   = (const float*)d_in[1];
  const float* Wh   = (const float*)d_in[2];
  const float* bias = (const float*)d_in[3];
  float* out = (float*)d_out;
  char* ws = (char*)d_ws;

  uint64_t* Pbuf = (uint64_t*)ws;              // 2*32*8*512*8 = 2,097,152 B
  uint64_t* zbuf = (uint64_t*)(ws + 2097152);  // 2*32*512*8  =   524,288 B

  hipMemsetAsync(ws, 0, 2621440, stream);  // reset tags (replay-safe)
  // Phase 1: gz|gr (fp16, bias folded) into d_out's first 134,217,728 bytes.
  gemm_gzr<<<4096, 256, 0, stream>>>(x, Wx, bias, (_Float16*)d_out);
  // Phase 2: scan consumes gzr rows before overwriting them with fp32 output.
  gru_scan<<<256, 1024, 0, stream>>>(x, Wx, Wh, bias, (const _Float16*)d_out,
                                     out, Pbuf, zbuf);
}

// Round 8
// 7109.541 us; speedup vs baseline: 1.5352x; 1.5352x over previous
//
#include <hip/hip_runtime.h>
#include <stdint.h>
#include <stddef.h>

// GRU (B=32, T=2048, I=H=512, fp32 in/out).
// Phase 1 (MFMA GEMM): gz|gr = x@Wx{z,r}+bias -> fp16 INTO d_out (row-aliased,
//   consumed before overwritten); gh = x@Wxh+bias_h -> fp16 into d_ws (if it
//   fits; else fallback keeps Wxh in-scan).
// Phase 2 (persistent scan): 256 WGs x 512 thr = 32 batches x 8 slices.
//   R8 structural change: z/r hidden-side weights live in LDS (128 KB/WG,
//   fp16) — residency the register allocator can't take away (R4-R7: it
//   refused >64-128 VGPRs and re-pulled weights from L2 every step, the
//   ~4.3us/step wall). Candidate weights: only 32 u32/thread in regs.
//   Cross-WG exchange: tagged-u64 self-sync buffers (R3 protocol).

#define AGENT __HIP_MEMORY_SCOPE_AGENT

typedef _Float16 h2v __attribute__((ext_vector_type(2)));
typedef _Float16 half8 __attribute__((ext_vector_type(8)));
typedef float f32x4 __attribute__((ext_vector_type(4)));

__device__ __forceinline__ uint32_t pk2u(float a, float b) {
  h2v r; r[0] = (_Float16)a; r[1] = (_Float16)b;
  return __builtin_bit_cast(uint32_t, r);
}
__device__ __forceinline__ h2v bc2(uint32_t u) { return __builtin_bit_cast(h2v, u); }
__device__ __forceinline__ float dot2f(h2v a, h2v b, float c) {
#if __has_builtin(__builtin_amdgcn_fdot2)
  return __builtin_amdgcn_fdot2(a, b, c, false);
#else
  return fmaf((float)a[1], (float)b[1], fmaf((float)a[0], (float)b[0], c));
#endif
}
__device__ __forceinline__ float sigmoidf_(float x) { return 1.0f / (1.0f + __expf(-x)); }
__device__ __forceinline__ float tanhf_(float x) { return 1.0f - 2.0f / (1.0f + __expf(2.0f * x)); }
__device__ __forceinline__ uint64_t ald64(const uint64_t* p) {
  return __hip_atomic_load(p, __ATOMIC_RELAXED, AGENT);
}
__device__ __forceinline__ void ast64(uint64_t* p, uint64_t v) {
  __hip_atomic_store(p, v, __ATOMIC_RELAXED, AGENT);
}

// ---------------- Phase 1: gate GEMM  [65536 x 512] @ [512 x N*128] -> fp16 ----------------
__global__ __launch_bounds__(256) void gemm_gx(const float* __restrict__ x,
                                               const float* __restrict__ Wx,
                                               const float* __restrict__ bias,
                                               _Float16* gzr,   // [65536][1024] (aliases out)
                                               _Float16* gh,    // [65536][512] in ws (opt)
                                               int nTN) {
  __shared__ alignas(16) _Float16 Alds[128 * 68];
  __shared__ alignas(16) _Float16 Blds[128 * 68];
  const int tid = threadIdx.x;
  const int bid = blockIdx.x;
  const int tm = bid / nTN, tn = bid % nTN;
  const int m0 = tm << 7, n0 = tn << 7;  // n0 in [0, nTN*128)
  const int lane = tid & 63;
  const int wv = tid >> 6, wm = wv >> 1, wn = wv & 1;
  const int l15 = lane & 15, lhi = lane >> 4;
  f32x4 acc[4][4] = {};

  for (int k0 = 0; k0 < 512; k0 += 64) {
#pragma unroll
    for (int r = 0; r < 8; ++r) {
      int m = r * 16 + (tid >> 4);
      int k = (tid & 15) * 4;
      float4 v = *(const float4*)&x[(size_t)(m0 + m) * 512 + k0 + k];
      union { _Float16 h[4]; uint2 u; } cv;
      cv.h[0] = (_Float16)v.x; cv.h[1] = (_Float16)v.y;
      cv.h[2] = (_Float16)v.z; cv.h[3] = (_Float16)v.w;
      *(uint2*)&Alds[m * 68 + k] = cv.u;
    }
#pragma unroll
    for (int u = 0; u < 8; ++u) {
      int n = tid & 127;
      int k = (tid >> 7) * 32 + u * 4;
      int ng = n0 + n;
      const float* wp = Wx + ((size_t)(ng >> 9) << 18) + (size_t)(k0 + k) * 512 + (ng & 511);
      union { _Float16 h[4]; uint2 u2; } cv;
      cv.h[0] = (_Float16)wp[0];    cv.h[1] = (_Float16)wp[512];
      cv.h[2] = (_Float16)wp[1024]; cv.h[3] = (_Float16)wp[1536];
      *(uint2*)&Blds[n * 68 + k] = cv.u2;
    }
    __syncthreads();
#pragma unroll
    for (int kk = 0; kk < 2; ++kk) {
      int q = kk * 4 + lhi;
      half8 af[4], bf[4];
#pragma unroll
      for (int fm = 0; fm < 4; ++fm) {
        const _Float16* pa = &Alds[(wm * 64 + fm * 16 + l15) * 68 + q * 8];
        union { uint2 u[2]; half8 h; } cv;
        cv.u[0] = *(const uint2*)pa; cv.u[1] = *(const uint2*)(pa + 4);
        af[fm] = cv.h;
      }
#pragma unroll
      for (int fn = 0; fn < 4; ++fn) {
        const _Float16* pb = &Blds[(wn * 64 + fn * 16 + l15) * 68 + q * 8];
        union { uint2 u[2]; half8 h; } cv;
        cv.u[0] = *(const uint2*)pb; cv.u[1] = *(const uint2*)(pb + 4);
        bf[fn] = cv.h;
      }
#pragma unroll
      for (int fm = 0; fm < 4; ++fm)
#pragma unroll
        for (int fn = 0; fn < 4; ++fn)
          acc[fm][fn] = __builtin_amdgcn_mfma_f32_16x16x32_f16(af[fm], bf[fn], acc[fm][fn], 0, 0, 0);
    }
    __syncthreads();
  }
#pragma unroll
  for (int fn = 0; fn < 4; ++fn) {
    int col = n0 + wn * 64 + fn * 16 + l15;
    float bv = bias[col];
#pragma unroll
    for (int fm = 0; fm < 4; ++fm) {
#pragma unroll
      for (int q2 = 0; q2 < 4; ++q2) {
        int row = m0 + wm * 64 + fm * 16 + lhi * 4 + q2;
        _Float16 val = (_Float16)(acc[fm][fn][q2] + bv);
        if (n0 < 1024) gzr[(size_t)row * 1024 + col] = val;
        else           gh[(size_t)row * 512 + (col - 1024)] = val;
      }
    }
  }
}

// ---------------- Phase 2: persistent scan ----------------
// GH=true: gh precomputed (bias folded); GH=false: Wxh in regs, x staged.
template <bool GH>
__global__ __launch_bounds__(512) void gru_scan(
    const float* __restrict__ x,
    const float* __restrict__ Wx,
    const float* __restrict__ Wh,
    const float* __restrict__ bias,
    const _Float16* gzr,            // [65536][1024] (aliases out)
    const _Float16* gh,             // [65536][512] (GH mode)
    float* out,                     // [32][2048][512] + [32][512]
    uint64_t* __restrict__ Pbuf,    // [2][32][8][512] tagged
    uint64_t* __restrict__ zbuf) {  // [2][32][512] tagged
  // z/r weights: [gate][col][k], row stride 516 halfs (b64-aligned, low-conflict)
  __shared__ alignas(16) float zrp[2][8][64];       // per-wave z/r partials
  __shared__ alignas(16) _Float16 wzr[2 * 64 * 516];
  __shared__ alignas(16) _Float16 h16[512];
  __shared__ alignas(16) _Float16 rh16[64];
  __shared__ alignas(16) _Float16 x16s[64];

  const int T = threadIdx.x;
  const int bid = blockIdx.x;
  const int xcd = bid & 7, ii = bid >> 3;
  const int batch = xcd * 4 + (ii >> 3);  // 8 WGs/batch share an XCD (heuristic)
  const int slice = ii & 7;
  const int wv = T >> 6;   // wave id = z/r K-octant
  const int ln = T & 63;   // lane = column-in-slice for z/r
  const int n = T;         // candidate output column

  // ---- fill z/r weight LDS (one-time; coalesced 256B global chunks) ----
  {
    const int cc = T & 63, kb = T >> 6;
#pragma unroll 4
    for (int g = 0; g < 2; ++g) {
      const float* W = Wh + (size_t)g * 262144 + slice * 64 + cc;
      for (int i = 0; i < 64; ++i) {
        int k = kb + 8 * i;
        wzr[(g * 64 + cc) * 516 + k] = (_Float16)W[(size_t)k * 512];
      }
    }
  }
  // ---- candidate weights: 32 words/thread (64 in fallback) ----
  uint32_t wh2[32], wx2[GH ? 1 : 32];
  {
    const float* Whh = Wh + 524288;
#pragma unroll
    for (int j = 0; j < 32; ++j) {
      int kk = slice * 64 + 2 * j;
      wh2[j] = pk2u(Whh[(size_t)kk * 512 + n], Whh[(size_t)(kk + 1) * 512 + n]);
    }
    if (!GH) {
      const float* Wxh = Wx + 524288;
#pragma unroll
      for (int j = 0; j < 32; ++j) {
        int kk = slice * 64 + 2 * j;
        wx2[j] = pk2u(Wxh[(size_t)kk * 512 + n], Wxh[(size_t)(kk + 1) * 512 + n]);
      }
    }
  }
  const float bh = bias[1024 + n];

  float hreg = 0.0f;
  h16[T] = (_Float16)0.0f;

  const size_t rowbase = (size_t)batch * 2048;
  // prefetch registers (rotated: *_cur consumed this step, *_p holds next row)
  float gz_p = 0.f, gr_p = 0.f, gz_cur = 0.f, gr_cur = 0.f, x_p = 0.f;
  float gh_p = 0.f, gh_cur = 0.f;
  if (T < 64)       gz_p = (float)gzr[rowbase * 1024 + slice * 64 + T];
  else if (T < 128) gr_p = (float)gzr[rowbase * 1024 + 512 + slice * 64 + (T - 64)];
  if (GH) gh_p = (float)gh[rowbase * 512 + n];
  else if (T < 64) x_p = x[rowbase * 512 + slice * 64 + T];

  uint64_t* Pmine = Pbuf + ((size_t)batch * 8 + slice) * 512 + n;
  const uint64_t* Pread = Pbuf + ((size_t)batch * 8) * 512 + n;
  uint64_t* zmine = zbuf + (size_t)batch * 512 + slice * 64 + ln;
  const uint64_t* zread = zbuf + (size_t)batch * 512 + n;

  for (int t = 0; t < 2048; ++t) {
    if (t > 0) {
      // combine step t-1: spin-gather 8 tagged partials + tagged z
      const size_t po = ((t - 1) & 1) ? 131072 : 0;
      const size_t zo = ((t - 1) & 1) ? 16384 : 0;
      const uint32_t want = (uint32_t)t;
      uint64_t v[8];
#pragma unroll
      for (int g = 0; g < 8; ++g) v[g] = ald64(Pread + po + (size_t)g * 512);
      uint64_t zv = ald64(zread + zo);
      for (;;) {
        bool ok = true;
        if ((uint32_t)(zv >> 32) != want) { zv = ald64(zread + zo); ok = false; }
#pragma unroll
        for (int g = 0; g < 8; ++g)
          if ((uint32_t)(v[g] >> 32) != want) { v[g] = ald64(Pread + po + (size_t)g * 512); ok = false; }
        if (ok) break;
        __builtin_amdgcn_s_sleep(1);
      }
      float hsum = 0.f;
#pragma unroll
      for (int g = 0; g < 8; ++g) hsum += __uint_as_float((uint32_t)v[g]);
      float zf = __uint_as_float((uint32_t)zv);
      float htil = tanhf_(GH ? (gh_cur + hsum) : (bh + hsum));
      float hn = fmaf(zf, htil - hreg, hreg);
      if (slice == 0) out[(rowbase + (t - 1)) * 512 + n] = hn;
      hreg = hn;
      h16[T] = (_Float16)hn;
    }
    // rotate prefetches (row t becomes current)
    gz_cur = gz_p; gr_cur = gr_p;
    if (GH) gh_cur = gh_p;
    else if (T < 64) x16s[T] = (_Float16)x_p;
    __syncthreads();  // B1: h16 (and x16s) published
    if (t < 2047) {
      size_t r1 = rowbase + t + 1;
      if (T < 64)       gz_p = (float)gzr[r1 * 1024 + slice * 64 + T];
      else if (T < 128) gr_p = (float)gzr[r1 * 1024 + 512 + slice * 64 + (T - 64)];
      if (GH) gh_p = (float)gh[r1 * 512 + n];
      else if (T < 64) x_p = x[r1 * 512 + slice * 64 + T];
    }

    // ---- z/r GEMV from LDS: wave wv covers k in [64*wv, 64*wv+64) for col ln ----
    float za = 0.f, ra = 0.f;
    {
      const _Float16* wzp = &wzr[(0 * 64 + ln) * 516 + 64 * wv];
      const _Float16* wrp = &wzr[(1 * 64 + ln) * 516 + 64 * wv];
      const _Float16* hp = &h16[64 * wv];
#pragma unroll
      for (int j = 0; j < 16; ++j) {
        uint2 wzu = *(const uint2*)(wzp + 4 * j);   // b64, lanes stride 516h -> low conflict
        uint2 wru = *(const uint2*)(wrp + 4 * j);
        uint2 hu = *(const uint2*)(hp + 4 * j);     // uniform -> broadcast
        za = dot2f(bc2(hu.x), bc2(wzu.x), za);
        za = dot2f(bc2(hu.y), bc2(wzu.y), za);
        ra = dot2f(bc2(hu.x), bc2(wru.x), ra);
        ra = dot2f(bc2(hu.y), bc2(wru.y), ra);
      }
    }
    zrp[0][wv][ln] = za;
    zrp[1][wv][ln] = ra;
    __syncthreads();  // Bzr: partials complete
    const size_t po = (t & 1) ? 131072 : 0;
    const size_t zo = (t & 1) ? 16384 : 0;
    const uint64_t tagw = ((uint64_t)(uint32_t)(t + 1)) << 32;
    if (T < 128) {
      const int g = T >> 6, c = T & 63;
      float sum = 0.f;
#pragma unroll
      for (int s2 = 0; s2 < 8; ++s2) sum += zrp[g][s2][c];
      if (g == 0) {
        float z = sigmoidf_(sum + gz_cur);
        ast64(zmine + zo, tagw | (uint32_t)__float_as_uint(z));
      } else {
        float r = sigmoidf_(sum + gr_cur);
        rh16[c] = (_Float16)(r * (float)h16[slice * 64 + c]);
      }
    }
    __syncthreads();  // B2: rh16 visible (and zrp safe to rewrite next iter)

    // ---- candidate partial: rh_slice @ Whh (+ x_slice @ Wxh in fallback) ----
    float pa = 0.f;
#pragma unroll
    for (int j = 0; j < 16; ++j) {
      uint2 ru = *(const uint2*)&rh16[4 * j];  // uniform -> broadcast
      pa = dot2f(bc2(ru.x), bc2(wh2[2 * j]), pa);
      pa = dot2f(bc2(ru.y), bc2(wh2[2 * j + 1]), pa);
    }
    if (!GH) {
#pragma unroll
      for (int j = 0; j < 16; ++j) {
        uint2 xu = *(const uint2*)&x16s[4 * j];
        pa = dot2f(bc2(xu.x), bc2(wx2[2 * j]), pa);
        pa = dot2f(bc2(xu.y), bc2(wx2[2 * j + 1]), pa);
      }
    }
    ast64(Pmine + po, tagw | (uint32_t)__float_as_uint(pa));
    if (!GH) __syncthreads();  // B3 (fallback): protect x16s vs next publish
  }

  // epilogue: finalize step 2047 (parity 1, tag 2048)
  {
    const uint32_t want = 2048u;
    uint64_t v[8];
#pragma unroll
    for (int g = 0; g < 8; ++g) v[g] = ald64(Pread + 131072 + (size_t)g * 512);
    uint64_t zv = ald64(zread + 16384);
    for (;;) {
      bool ok = true;
      if ((uint32_t)(zv >> 32) != want) { zv = ald64(zread + 16384); ok = false; }
#pragma unroll
      for (int g = 0; g < 8; ++g)
        if ((uint32_t)(v[g] >> 32) != want) { v[g] = ald64(Pread + 131072 + (size_t)g * 512); ok = false; }
      if (ok) break;
      __builtin_amdgcn_s_sleep(1);
    }
    float hsum = 0.f;
#pragma unroll
    for (int g = 0; g < 8; ++g) hsum += __uint_as_float((uint32_t)v[g]);
    float zf = __uint_as_float((uint32_t)zv);
    float htil = tanhf_(GH ? (gh_cur + hsum) : (bh + hsum));
    float hn = fmaf(zf, htil - hreg, hreg);
    if (slice == 0) {
      out[(rowbase + 2047) * 512 + n] = hn;
      out[(size_t)32 * 2048 * 512 + (size_t)batch * 512 + n] = hn;
    }
  }
}

extern "C" void kernel_launch(void* const* d_in, const int* in_sizes, int n_in,
                              void* d_out, int out_size, void* d_ws, size_t ws_size,
                              hipStream_t stream) {
  (void)in_sizes; (void)n_in; (void)out_size;
  const float* x    = (const float*)d_in[0];
  const float* Wx   = (const float*)d_in[1];
  const float* Wh   = (const float*)d_in[2];
  const float* bias = (const float*)d_in[3];
  float* out = (float*)d_out;
  char* ws = (char*)d_ws;

  uint64_t* Pbuf = (uint64_t*)ws;              // 2*32*8*512*8 = 2,097,152 B
  uint64_t* zbuf = (uint64_t*)(ws + 2097152);  // 2*32*512*8  =   524,288 B
  _Float16* gh   = (_Float16*)(ws + 2621440);  // 65536*512*2 = 67,108,864 B (opt)

  hipMemsetAsync(ws, 0, 2621440, stream);  // reset exchange tags (replay-safe)
  const bool gh_mode = ws_size >= (size_t)2621440 + 67108864ull;
  if (gh_mode) {
    gemm_gx<<<512 * 12, 256, 0, stream>>>(x, Wx, bias, (_Float16*)d_out, gh, 12);
    gru_scan<true><<<256, 512, 0, stream>>>(x, Wx, Wh, bias, (const _Float16*)d_out,
                                            gh, out, Pbuf, zbuf);
  } else {
    gemm_gx<<<512 * 8, 256, 0, stream>>>(x, Wx, bias, (_Float16*)d_out, gh, 8);
    gru_scan<false><<<256, 512, 0, stream>>>(x, Wx, Wh, bias, (const _Float16*)d_out,
                                             gh, out, Pbuf, zbuf);
  }
}